// Round 19
// baseline (311.559 us; speedup 1.0000x reference)
//
#include <hip/hip_runtime.h>

typedef unsigned short u16;
typedef __attribute__((ext_vector_type(2))) float f32x2;
typedef __attribute__((ext_vector_type(4))) float f32x4;
typedef __attribute__((ext_vector_type(8))) short s16x8;
typedef __attribute__((ext_vector_type(8))) u16 u16x8;
typedef __attribute__((ext_vector_type(4))) u16 u16x4;

#define NB 16
#define CD 512
#define NS 4096
#define NHD 8

#define SBAR  __builtin_amdgcn_s_barrier()
#define SCHED __builtin_amdgcn_sched_barrier(0)
#define PRIO1 __builtin_amdgcn_s_setprio(1)
#define PRIO0 __builtin_amdgcn_s_setprio(0)

__device__ __forceinline__ float bf2f(u16 u){
  union { unsigned int i; float f; } z; z.i = ((unsigned int)u) << 16; return z.f;
}
__device__ __forceinline__ u16 f2bf(float f){
  union { float f; unsigned int i; } z; z.f = f;
  unsigned int i = z.i;
  return (u16)((i + 0x7fffu + ((i >> 16) & 1u)) >> 16);
}
__device__ __forceinline__ float gelu_f(float x){
  return 0.5f * x * (1.0f + erff(x * 0.70710678118654752440f));
}
__device__ __forceinline__ void gl_lds16(const u16* g, u16* l){
  __builtin_amdgcn_global_load_lds((const __attribute__((address_space(1))) void*)(g),
                                   (__attribute__((address_space(3))) void*)(l), 16, 0, 0);
}

// ---------------- K0: weights -> bf16 (g1 folded into w_qkv) ----------------
__global__ void prep_w_k(const float* __restrict__ wqkv, const float* __restrict__ g1,
                         const float* __restrict__ wout, u16* __restrict__ w1b,
                         u16* __restrict__ w2b){
  int i = blockIdx.x * 256 + threadIdx.x;
  if (i < 1536*512) {
    w1b[i] = f2bf(wqkv[i] * g1[i & 511]);
  } else {
    int j = i - 1536*512;
    w2b[j] = f2bf(wout[j]);
  }
}

// ------- K1: ChanLN over c, single global read, bf16 LDS staging -----------
__global__ __launch_bounds__(512) void ln1t_k(const float* __restrict__ fmap,
                                              u16* __restrict__ xlnT){
  int b = blockIdx.y, n0 = blockIdx.x * 32;
  int t = threadIdx.x;
  int lane = t & 63, wv = t >> 6;
  __shared__ u16 Lb[512][40];
  __shared__ u16 Tt[64][36];
  __shared__ float red1[8][8][4], red2[8][8][4];
  __shared__ float mean_s[32], rstd_s[32];

  int ng = t & 7;
  float s1[4] = {0,0,0,0}, s2[4] = {0,0,0,0};
  const float* fb = fmap + ((size_t)b*CD)*NS + n0 + ng*4;
  #pragma unroll
  for (int it = 0; it < 8; ++it){
    int q = it*512 + t;
    int c = q >> 3;
    f32x4 v = *(const f32x4*)&fb[(size_t)c*NS];
    u16x4 pk;
    #pragma unroll
    for (int j = 0; j < 4; ++j){
      pk[j] = f2bf(v[j]);
      s1[j] += v[j]; s2[j] += v[j]*v[j];
    }
    *(u16x4*)&Lb[c][ng*4] = pk;
  }
  #pragma unroll
  for (int off = 8; off < 64; off <<= 1)
    #pragma unroll
    for (int j = 0; j < 4; ++j){
      s1[j] += __shfl_xor(s1[j], off, 64);
      s2[j] += __shfl_xor(s2[j], off, 64);
    }
  if (lane < 8){
    #pragma unroll
    for (int j = 0; j < 4; ++j){ red1[wv][lane][j] = s1[j]; red2[wv][lane][j] = s2[j]; }
  }
  __syncthreads();
  if (t < 32){
    int g = t >> 2, j = t & 3;
    float a = 0.f, bq = 0.f;
    #pragma unroll
    for (int w = 0; w < 8; ++w){ a += red1[w][g][j]; bq += red2[w][g][j]; }
    float mn = a * (1.f/512.f);
    float var = bq * (1.f/512.f) - mn*mn;
    mean_s[t] = mn; rstd_s[t] = rsqrtf(var + 1e-5f);
  }
  __syncthreads();

  for (int ct = 0; ct < 8; ++ct){
    {
      int cl = t >> 3, n4 = (t & 7) * 4;
      u16x4 xv = *(const u16x4*)&Lb[ct*64 + cl][n4];
      u16x4 pk;
      #pragma unroll
      for (int j = 0; j < 4; ++j)
        pk[j] = f2bf((bf2f(xv[j]) - mean_s[n4+j]) * rstd_s[n4+j]);
      *(u16x4*)&Tt[cl][n4] = pk;
    }
    __syncthreads();
    {
      int nr = t >> 4, c4 = t & 15;
      u16x4 w;
      #pragma unroll
      for (int j = 0; j < 4; ++j) w[j] = Tt[c4*4 + j][nr];
      *(u16x4*)&xlnT[((size_t)b*NS + n0 + nr)*CD + ct*64 + c4*4] = w;
    }
    __syncthreads();
  }
}

// ---------- K2a: q-GEMM (512 rows), r12 loop verbatim -----------------------
__global__ __launch_bounds__(512) void gemm1q_k(const u16* __restrict__ A,
                                                const u16* __restrict__ Bm,
                                                u16* __restrict__ Q){
  __shared__ u16 lds[8][8192];   // [slot*4+half]
  int bi = blockIdx.x;
  int xcd = bi & 7, r2 = bi >> 3;   // 0..63
  int yy = r2 & 1, gi = r2 >> 1;
  int g  = gi*8 + xcd;
  int x  = g & 15, z = g >> 4;
  int o0 = yy*256, bn0 = x*256;
  int t = threadIdx.x;
  int lane = t & 63, wv = t >> 6;
  int wm = wv >> 2, wn = wv & 3;
  int fr = lane & 15, fg = lane >> 4;
  const u16* Ab = A + (size_t)o0*512;
  const u16* Bb = Bm + ((size_t)z*NS + bn0)*512;
  int li8 = lane >> 3, scn = lane & 7;

  f32x4 acc[8][4];
  #pragma unroll
  for (int i=0;i<8;++i)
    #pragma unroll
    for (int j=0;j<4;++j) acc[i][j] = (f32x4){0.f,0.f,0.f,0.f};
  s16x8 afr[4][2];
  s16x8 bfr[2][2][2];

  auto stH = [&](int slot, int half, int kt){
    #pragma unroll
    for (int it=0; it<2; ++it){
      int li = it*64 + wv*8 + li8;
      int q  = scn ^ (li & 7);
      int row;
      if (half < 2) row = ((li>>6)<<7) + half*64 + (li & 63);
      else          row = ((li>>5)<<6) + (half-2)*32 + (li & 31);
      const u16* G = (half < 2) ? Ab : Bb;
      gl_lds16(G + (size_t)row*512 + kt + q*8, &lds[slot*4+half][it*4096 + wv*512]);
    }
  };
  auto ldA = [&](int slot, int mq){
    #pragma unroll
    for (int mr=0;mr<4;++mr)
      #pragma unroll
      for (int ks=0;ks<2;++ks){
        int li = wm*64 + mr*16 + fr;
        int c8 = (ks*4+fg) ^ (li & 7);
        afr[mr][ks] = *(const s16x8*)&lds[slot*4+mq][li*64 + c8*8];
      }
  };
  auto ldB = [&](int slot, int nq){
    #pragma unroll
    for (int nr=0;nr<2;++nr)
      #pragma unroll
      for (int ks=0;ks<2;++ks){
        int li = wn*32 + nr*16 + fr;
        int c8 = (ks*4+fg) ^ (li & 7);
        bfr[nq][nr][ks] = *(const s16x8*)&lds[slot*4+2+nq][li*64 + c8*8];
      }
  };
  auto mm = [&](int mq, int nq){
    #pragma unroll
    for (int mr=0;mr<4;++mr)
      #pragma unroll
      for (int nr=0;nr<2;++nr)
        #pragma unroll
        for (int ks=0;ks<2;++ks)
          acc[mq*4+mr][nq*2+nr] = __builtin_amdgcn_mfma_f32_16x16x32_bf16(
              afr[mr][ks], bfr[nq][nr][ks], acc[mq*4+mr][nq*2+nr], 0,0,0);
  };

  stH(0,0,0); stH(0,2,0); stH(0,3,0); stH(0,1,0);
  asm volatile("s_waitcnt vmcnt(2)" ::: "memory");
  SBAR; SCHED;

  #pragma unroll
  for (int kt=0; kt<8; ++kt){
    int slot = kt & 1, ns = slot ^ 1, kn = (kt+1)*64;
    bool F = kt < 7;
    ldA(slot,0); ldB(slot,0); ldB(slot,1);
    if (F){ stH(ns,0,kn); stH(ns,2,kn); stH(ns,3,kn); }
    PRIO1; mm(0,0); mm(0,1); PRIO0;
    if (F) asm volatile("s_waitcnt vmcnt(6)" ::: "memory");
    else   asm volatile("s_waitcnt vmcnt(0)" ::: "memory");
    SBAR; SCHED;
    ldA(slot,1);
    if (F) stH(ns,1,kn);
    PRIO1; mm(1,1); mm(1,0); PRIO0;
    if (F) asm volatile("s_waitcnt vmcnt(2)" ::: "memory");
    SBAR; SCHED;
  }

  size_t cb = (size_t)z * 512 * NS;
  #pragma unroll
  for (int mq=0;mq<2;++mq)
    #pragma unroll
    for (int mr=0;mr<4;++mr)
      #pragma unroll
      for (int nq=0;nq<2;++nq)
        #pragma unroll
        for (int nr=0;nr<2;++nr){
          int row = o0 + wm*128 + mq*64 + mr*16 + fg*4;
          int col = bn0 + wn*64 + nq*32 + nr*16 + fr;
          #pragma unroll
          for (int r=0;r<4;++r)
            Q[cb + (size_t)(row+r)*NS + col] = f2bf(acc[mq*4+mr][nq*2+nr][r]);
        }
}

// ---------- K2b: kv-GEMM + FUSED ctx partial (no k/v HBM round-trip) --------
__global__ __launch_bounds__(512) void gemm1kv_k(const u16* __restrict__ A,
                                                 const u16* __restrict__ Bm,
                                                 float* __restrict__ part,
                                                 float* __restrict__ mS){
  __shared__ u16 lds[8][8192];
  int bi = blockIdx.x;
  int xcd = bi & 7, r2 = bi >> 3;
  int hp = r2 & 3, gg = r2 >> 2;
  int g8 = gg*8 + xcd;
  int x  = g8 & 15, z = g8 >> 4;
  int bn0 = x*256;
  int t = threadIdx.x;
  int lane = t & 63, wv = t >> 6;
  int wm = wv >> 2, wn = wv & 3;
  int fr = lane & 15, fg = lane >> 4;
  const u16* Akb = A + (size_t)(512  + hp*128)*512;
  const u16* Avb = A + (size_t)(1024 + hp*128)*512;
  const u16* Bb  = Bm + ((size_t)z*NS + bn0)*512;
  int li8 = lane >> 3, scn = lane & 7;

  f32x4 acc[8][4];
  #pragma unroll
  for (int i=0;i<8;++i)
    #pragma unroll
    for (int j=0;j<4;++j) acc[i][j] = (f32x4){0.f,0.f,0.f,0.f};
  s16x8 afr[4][2];
  s16x8 bfr[2][2][2];

  auto stH = [&](int slot, int half, int kt){
    #pragma unroll
    for (int it=0; it<2; ++it){
      int li = it*64 + wv*8 + li8;
      int q  = scn ^ (li & 7);
      if (half < 2){
        int rr = half*64 + (li & 63);
        const u16* G = it ? Avb : Akb;
        gl_lds16(G + (size_t)rr*512 + kt + q*8, &lds[slot*4+half][it*4096 + wv*512]);
      } else {
        int row = ((li>>5)<<6) + (half-2)*32 + (li & 31);
        gl_lds16(Bb + (size_t)row*512 + kt + q*8, &lds[slot*4+half][it*4096 + wv*512]);
      }
    }
  };
  auto ldA = [&](int slot, int mq){
    #pragma unroll
    for (int mr=0;mr<4;++mr)
      #pragma unroll
      for (int ks=0;ks<2;++ks){
        int li = wm*64 + mr*16 + fr;
        int c8 = (ks*4+fg) ^ (li & 7);
        afr[mr][ks] = *(const s16x8*)&lds[slot*4+mq][li*64 + c8*8];
      }
  };
  auto ldB = [&](int slot, int nq){
    #pragma unroll
    for (int nr=0;nr<2;++nr)
      #pragma unroll
      for (int ks=0;ks<2;++ks){
        int li = wn*32 + nr*16 + fr;
        int c8 = (ks*4+fg) ^ (li & 7);
        bfr[nq][nr][ks] = *(const s16x8*)&lds[slot*4+2+nq][li*64 + c8*8];
      }
  };
  auto mm = [&](int mq, int nq){
    #pragma unroll
    for (int mr=0;mr<4;++mr)
      #pragma unroll
      for (int nr=0;nr<2;++nr)
        #pragma unroll
        for (int ks=0;ks<2;++ks)
          acc[mq*4+mr][nq*2+nr] = __builtin_amdgcn_mfma_f32_16x16x32_bf16(
              afr[mr][ks], bfr[nq][nr][ks], acc[mq*4+mr][nq*2+nr], 0,0,0);
  };

  stH(0,0,0); stH(0,2,0); stH(0,3,0); stH(0,1,0);
  asm volatile("s_waitcnt vmcnt(2)" ::: "memory");
  SBAR; SCHED;

  #pragma unroll
  for (int kt=0; kt<8; ++kt){
    int slot = kt & 1, ns = slot ^ 1, kn = (kt+1)*64;
    bool F = kt < 7;
    ldA(slot,0); ldB(slot,0); ldB(slot,1);
    if (F){ stH(ns,0,kn); stH(ns,2,kn); stH(ns,3,kn); }
    PRIO1; mm(0,0); mm(0,1); PRIO0;
    if (F) asm volatile("s_waitcnt vmcnt(6)" ::: "memory");
    else   asm volatile("s_waitcnt vmcnt(0)" ::: "memory");
    SBAR; SCHED;
    ldA(slot,1);
    if (F) stH(ns,1,kn);
    PRIO1; mm(1,1); mm(1,0); PRIO0;
    if (F) asm volatile("s_waitcnt vmcnt(2)" ::: "memory");
    SBAR; SCHED;
  }

  // ---- Phase 1: acc -> KT/VT tiles ----
  if (wm == 0){
    #pragma unroll
    for (int mq=0;mq<2;++mq)
      #pragma unroll
      for (int mr=0;mr<4;++mr)
        #pragma unroll
        for (int nj=0;nj<4;++nj){
          int nq = nj>>1, nr = nj&1;
          #pragma unroll
          for (int r=0;r<4;++r){
            int d  = mr*16 + fg*4 + r;
            int nl = wn*64 + nq*32 + nr*16 + fr;
            int hh = nl >> 7, n1 = nl & 127;
            lds[mq*2+hh][d*128 + (n1 ^ ((d&7)<<3))] = f2bf(__expf(acc[mq*4+mr][nj][r]));
          }
        }
  } else {
    float ss[2][4];
    #pragma unroll
    for (int mq=0;mq<2;++mq)
      #pragma unroll
      for (int nj=0;nj<4;++nj){
        float s = 0.f;
        #pragma unroll
        for (int mr=0;mr<4;++mr)
          #pragma unroll
          for (int r=0;r<4;++r){ float v = acc[mq*4+mr][nj][r]; s += v*v; }
        s += __shfl_xor(s, 16, 64);
        s += __shfl_xor(s, 32, 64);
        ss[mq][nj] = rsqrtf(s);
      }
    #pragma unroll
    for (int mq=0;mq<2;++mq)
      #pragma unroll
      for (int mr=0;mr<4;++mr)
        #pragma unroll
        for (int nj=0;nj<4;++nj){
          int nq = nj>>1, nr = nj&1;
          #pragma unroll
          for (int r=0;r<4;++r){
            int e  = mr*16 + fg*4 + r;
            int nl = wn*64 + nq*32 + nr*16 + fr;
            int hh = nl >> 7, n1 = nl & 127;
            lds[4 + mq*2+hh][e*128 + (n1 ^ ((e&7)<<3))] = f2bf(acc[mq*4+mr][nj][r] * ss[mq][nj]);
          }
        }
  }
  __syncthreads();

  // ---- Phase 2: ctx MFMA + sloc ----
  int eg = wv >> 2, ej = wv & 3, ksl = ej & 1;
  const u16* KTt = &lds[eg*2 + (ej>>1)][0];
  const u16* VTt = &lds[4 + eg*2 + (ej>>1)][0];
  f32x4 a2[4][4];
  #pragma unroll
  for (int i=0;i<4;++i)
    #pragma unroll
    for (int j=0;j<4;++j) a2[i][j] = (f32x4){0.f,0.f,0.f,0.f};
  #pragma unroll
  for (int ks2=0; ks2<2; ++ks2){
    int kc = ksl*64 + ks2*32 + fg*8;
    s16x8 af[4], bf_[4];
    #pragma unroll
    for (int i=0;i<4;++i){
      int ra = i*16 + fr;
      af[i]  = *(const s16x8*)&KTt[ra*128 + (kc ^ ((ra&7)<<3))];
      bf_[i] = *(const s16x8*)&VTt[ra*128 + (kc ^ ((ra&7)<<3))];
    }
    #pragma unroll
    for (int i=0;i<4;++i)
      #pragma unroll
      for (int j=0;j<4;++j)
        a2[i][j] = __builtin_amdgcn_mfma_f32_16x16x32_bf16(af[i], bf_[j], a2[i][j], 0,0,0);
  }
  float slc = 0.f;
  {
    int d = lane;
    #pragma unroll
    for (int cc=0; cc<8; ++cc){
      int c0 = ksl*64 + cc*8;
      u16x8 vv = *(const u16x8*)&KTt[d*128 + (c0 ^ ((d&7)<<3))];
      #pragma unroll
      for (int jj=0;jj<8;++jj) slc += bf2f(vv[jj]);
    }
  }
  __syncthreads();

  // ---- Phase 3: dumps + slocB ----
  if (ej >= 1){
    float* dbuf = (float*)&lds[eg*3 + (ej-1)][0];
    #pragma unroll
    for (int i=0;i<4;++i)
      #pragma unroll
      for (int j=0;j<4;++j)
        #pragma unroll
        for (int r=0;r<4;++r) dbuf[((i*4+j)*4+r)*64 + lane] = a2[i][j][r];
  }
  ((float*)&lds[6][0])[eg*256 + ej*64 + lane] = slc;
  __syncthreads();

  // ---- Phase 4: reduce + write ----
  int bh = z*8 + hp*2 + eg;
  size_t base = (size_t)bh*16 + x;
  if (ej == 0){
    #pragma unroll
    for (int bb=0; bb<3; ++bb){
      float* dbuf = (float*)&lds[eg*3 + bb][0];
      #pragma unroll
      for (int i=0;i<4;++i)
        #pragma unroll
        for (int j=0;j<4;++j)
          #pragma unroll
          for (int r=0;r<4;++r) a2[i][j][r] += dbuf[((i*4+j)*4+r)*64 + lane];
    }
    float* pp = part + base*4096;
    #pragma unroll
    for (int i=0;i<4;++i)
      #pragma unroll
      for (int j=0;j<4;++j)
        #pragma unroll
        for (int r=0;r<4;++r)
          pp[(i*16+fg*4+r)*64 + j*16+fr] = a2[i][j][r];
  } else if (ej == 1){
    float* sB = (float*)&lds[6][0];
    float s = sB[eg*256 + lane] + sB[eg*256 + 64 + lane]
            + sB[eg*256 + 128 + lane] + sB[eg*256 + 192 + lane];
    mS[base*128 + lane]      = 0.0f;
    mS[base*128 + 64 + lane] = s;
  }
}

// ---- K4b: merge 16 chunk partials -> ctx -----------------------------------
__global__ void ctxred_k(const float* __restrict__ part, const float* __restrict__ mS,
                         float* __restrict__ ctx){
  int bh = blockIdx.x, t = threadIdx.x;
  __shared__ float fs[16][64];
  if (t < 64){
    int d = t;
    float denom = 0.f;
    #pragma unroll
    for (int c=0;c<16;++c)
      denom += mS[((size_t)bh*16 + c)*128 + 64 + d];
    float inv = 1.0f / (denom * 4096.0f);
    #pragma unroll
    for (int c=0;c<16;++c) fs[c][d] = inv;
  }
  __syncthreads();
  #pragma unroll
  for (int i=0;i<16;++i){
    int idx = t + i*256;
    int d = idx >> 6;
    float s = 0.f;
    #pragma unroll
    for (int ch=0; ch<16; ++ch) s += fs[ch][d] * part[((size_t)bh*16 + ch)*4096 + idx];
    ctx[(size_t)bh*4096 + idx] = s;
  }
}

// --- K6: FUSED attn-out + GEMM2 + final ChanLN -> d_out ---------------------
// No A-staging: w2b (512KB) is L2-resident -> afr loaded directly from
// global (Common-mistake #7). LDS = Bh 16K + P 18K + cT 9.2K + invP (~44KB)
// -> multi-block/CU phase overlap. Attn MFMA operand-swapped (out[e][n]) so
// Bh writes are u16x4 (was 16 scalar stores, 2.9M conflicts). 2 barriers/head.
__global__ __launch_bounds__(512, 2) void gemm2f_k(const u16* __restrict__ A,
                                                   const u16* __restrict__ q,
                                                   const float* __restrict__ ctx,
                                                   const float* __restrict__ g2,
                                                   float* __restrict__ out){
  __shared__ u16 Bh[2][4096];
  __shared__ u16 P[128][72];
  __shared__ u16 cT[64][72];
  __shared__ float invP[128];
  int x = blockIdx.x, z = blockIdx.y;
  int n0 = x*128;
  int t = threadIdx.x;
  int lane = t & 63, wv = t >> 6;
  int wm = wv >> 1, wn = wv & 1;     // GEMM map: 4M x 2N
  int we2 = wv >> 2, nn = wv & 3;    // attn map: 2E x 4N
  int fr = lane & 15, fg = lane >> 4;
  const u16* Ab = A;

  f32x4 acc[8][4];
  #pragma unroll
  for (int i=0;i<8;++i)
    #pragma unroll
    for (int j=0;j<4;++j) acc[i][j] = (f32x4){0.f,0.f,0.f,0.f};
  s16x8 afr[4], bfr[4];

  auto ldAg = [&](int h, int kt2, int h2){       // direct global (L2-hot)
    #pragma unroll
    for (int mi=0;mi<4;++mi){
      int R = wm*128 + (h2*4+mi)*16 + fr;
      afr[mi] = *(const s16x8*)&Ab[(size_t)R*512 + h*64 + kt2*32 + fg*8];
    }
  };
  auto ldBh = [&](int kt2){
    #pragma unroll
    for (int nj=0;nj<4;++nj){
      int R = wn*64 + nj*16 + fr;
      int L = R & 63, hh = R >> 6;
      int c8 = (hh*4 + fg) ^ (L & 7);
      bfr[nj] = *(const s16x8*)&Bh[kt2][L*64 + c8*8];
    }
  };
  auto mm16 = [&](int h2){
    #pragma unroll
    for (int mi=0;mi<4;++mi)
      #pragma unroll
      for (int nj=0;nj<4;++nj)
        acc[h2*4+mi][nj] = __builtin_amdgcn_mfma_f32_16x16x32_bf16(
            afr[mi], bfr[nj], acc[h2*4+mi][nj], 0,0,0);
  };

  for (int h = 0; h < 8; ++h){
    // cT = bf16(ctx[h]^T)
    const float* cs = ctx + ((size_t)(z*8 + h))*4096;
    #pragma unroll
    for (int i=0;i<8;++i){
      int idx = i*512 + t;
      cT[idx & 63][idx >> 6] = f2bf(cs[idx]);
    }
    // softmax over d: 4 threads per n
    {
      int nl = wv*16 + fr;
      const u16* qb = q + ((size_t)(z*512 + h*64 + fg*16))*NS + n0 + nl;
      float p[16];
      float m = -3.0e38f;
      #pragma unroll
      for (int j=0;j<16;++j){ p[j] = bf2f(qb[(size_t)j*NS]); m = fmaxf(m, p[j]); }
      m = fmaxf(m, __shfl_xor(m, 16, 64));
      m = fmaxf(m, __shfl_xor(m, 32, 64));
      float s = 0.f;
      #pragma unroll
      for (int j=0;j<16;++j){ p[j] = __expf(p[j]-m); s += p[j]; }
      s += __shfl_xor(s, 16, 64);
      s += __shfl_xor(s, 32, 64);
      u16x8 pk;
      #pragma unroll
      for (int j=0;j<8;++j) pk[j] = f2bf(p[j]);
      *(u16x8*)&P[nl][fg*16] = pk;
      #pragma unroll
      for (int j=0;j<8;++j) pk[j] = f2bf(p[8+j]);
      *(u16x8*)&P[nl][fg*16+8] = pk;
      if (fg == 0) invP[nl] = 0.125f / s;
    }
    __syncthreads();     // (A): P,cT,invP ready; all GEMM(h-1) done

    // attn MFMA (swapped): out[e][n]; wave (we2,nn) -> e 32 x n 32
    f32x4 a2[2][2];
    #pragma unroll
    for (int i=0;i<2;++i)
      #pragma unroll
      for (int j=0;j<2;++j) a2[i][j] = (f32x4){0.f,0.f,0.f,0.f};
    #pragma unroll
    for (int ks=0; ks<2; ++ks){
      s16x8 afx[2], bfx[2];
      #pragma unroll
      for (int ei=0;ei<2;++ei)
        afx[ei] = *(const s16x8*)&cT[we2*32 + ei*16 + fr][ks*32 + fg*8];
      #pragma unroll
      for (int ni=0;ni<2;++ni)
        bfx[ni] = *(const s16x8*)&P[nn*32 + ni*16 + fr][ks*32 + fg*8];
      #pragma unroll
      for (int ei=0;ei<2;++ei)
        #pragma unroll
        for (int ni=0;ni<2;++ni)
          a2[ei][ni] = __builtin_amdgcn_mfma_f32_16x16x32_bf16(afx[ei], bfx[ni], a2[ei][ni], 0,0,0);
    }
    // gelu -> Bh[we2] (u16x4, ldBh-consumable layout)
    #pragma unroll
    for (int ei=0;ei<2;++ei)
      #pragma unroll
      for (int ni=0;ni<2;++ni){
        int n = nn*32 + ni*16 + fr;
        float ip = invP[n];
        u16x4 w4;
        #pragma unroll
        for (int r=0;r<4;++r) w4[r] = f2bf(gelu_f(a2[ei][ni][r] * ip));
        int e32 = ei*16 + fg*4;
        int chunk = e32 >> 3, sub = e32 & 7;
        int L = n & 63, hh = n >> 6;
        int c8 = (hh*4 + chunk) ^ (L & 7);
        *(u16x4*)&Bh[we2][L*64 + c8*8 + sub] = w4;
      }
    __syncthreads();     // (B): Bh ready; attn done (P,cT free)

    // GEMM: 2 k-tiles, A direct from global
    #pragma unroll
    for (int kt2=0; kt2<2; ++kt2){
      ldBh(kt2);
      ldAg(h,kt2,0); PRIO1; mm16(0); PRIO0;
      ldAg(h,kt2,1); PRIO1; mm16(1); PRIO0;
    }
  }

  __syncthreads();
  // ---- fused LN2 (scratch aliased onto P) ----
  float* red1 = (float*)&P[0][0];
  float* red2 = red1 + 512;
  float* ms   = red2 + 512;
  float* rs   = ms + 128;
  float s1[4], s2[4];
  #pragma unroll
  for (int nj=0;nj<4;++nj){
    float a = 0.f, b2 = 0.f;
    #pragma unroll
    for (int mi=0;mi<8;++mi)
      #pragma unroll
      for (int r=0;r<4;++r){ float v = acc[mi][nj][r]; a += v; b2 += v*v; }
    s1[nj] = a; s2[nj] = b2;
  }
  #pragma unroll
  for (int off=16; off<64; off<<=1)
    #pragma unroll
    for (int nj=0;nj<4;++nj){
      s1[nj] += __shfl_xor(s1[nj], off, 64);
      s2[nj] += __shfl_xor(s2[nj], off, 64);
    }
  if (fg == 0){
    #pragma unroll
    for (int nj=0;nj<4;++nj){
      int c = wn*64 + nj*16 + fr;
      red1[wm*128 + c] = s1[nj];
      red2[wm*128 + c] = s2[nj];
    }
  }
  __syncthreads();
  if (t < 128){
    float a  = red1[t] + red1[128+t] + red1[256+t] + red1[384+t];
    float b2 = red2[t] + red2[128+t] + red2[256+t] + red2[384+t];
    float mn = a * (1.f/512.f);
    float var = b2 * (1.f/512.f) - mn*mn;
    ms[t] = mn; rs[t] = rsqrtf(var + 1e-5f);
  }
  __syncthreads();
  float mc[4], rc[4];
  #pragma unroll
  for (int nj=0;nj<4;++nj){
    int c = wn*64 + nj*16 + fr;
    mc[nj] = ms[c]; rc[nj] = rs[c];
  }
  float* ob = out + (size_t)z*CD*NS + n0;
  #pragma unroll
  for (int mi=0;mi<8;++mi)
    #pragma unroll
    for (int r=0;r<4;++r){
      int row = wm*128 + mi*16 + fg*4 + r;
      float gg = g2[row];
      #pragma unroll
      for (int nj=0;nj<4;++nj)
        ob[(size_t)row*NS + wn*64 + nj*16 + fr] = (acc[mi][nj][r] - mc[nj])*rc[nj]*gg;
    }
}

extern "C" void kernel_launch(void* const* d_in, const int* in_sizes, int n_in,
                              void* d_out, int out_size, void* d_ws, size_t ws_size,
                              hipStream_t stream) {
  const float* fmap = (const float*)d_in[0];
  const float* g1   = (const float*)d_in[1];
  const float* wqkv = (const float*)d_in[2];
  const float* wout = (const float*)d_in[3];
  const float* g2   = (const float*)d_in[4];
  float* out = (float*)d_out;

  char* ws = (char*)d_ws;
  size_t off = 0;
  auto alloc = [&](size_t bytes) -> void* {
    void* p = ws + off;
    off += (bytes + 255) & ~(size_t)255;
    return p;
  };
  u16*   q    = (u16*)alloc((size_t)16*512*4096*2);
  u16*   xlnT = (u16*)alloc((size_t)16*4096*512*2);
  float* part = (float*)alloc((size_t)128*16*4096*4);
  float* mS   = (float*)alloc((size_t)128*16*128*4);
  float* ctx  = (float*)alloc((size_t)128*4096*4);
  u16*   w1b  = (u16*)alloc((size_t)1536*512*2);
  u16*   w2b  = (u16*)alloc((size_t)512*512*2);
  if (off > ws_size) return;

  prep_w_k<<<4096, 256, 0, stream>>>(wqkv, g1, wout, w1b, w2b);
  ln1t_k<<<dim3(128,16), 512, 0, stream>>>(fmap, xlnT);
  gemm1q_k<<<512, 512, 0, stream>>>(w1b, xlnT, q);
  gemm1kv_k<<<1024, 512, 0, stream>>>(w1b, xlnT, part, mS);
  ctxred_k<<<128, 256, 0, stream>>>(part, mS, ctx);
  gemm2f_k<<<dim3(32,16), 512, 0, stream>>>(w2b, q, ctx, g2, out);
}

// Round 20
// 280.122 us; speedup vs baseline: 1.1122x; 1.1122x over previous
//
#include <hip/hip_runtime.h>

typedef unsigned short u16;
typedef __attribute__((ext_vector_type(2))) float f32x2;
typedef __attribute__((ext_vector_type(4))) float f32x4;
typedef __attribute__((ext_vector_type(8))) short s16x8;
typedef __attribute__((ext_vector_type(8))) u16 u16x8;
typedef __attribute__((ext_vector_type(4))) u16 u16x4;

#define NB 16
#define CD 512
#define NS 4096
#define NHD 8

#define SBAR  __builtin_amdgcn_s_barrier()
#define SCHED __builtin_amdgcn_sched_barrier(0)
#define PRIO1 __builtin_amdgcn_s_setprio(1)
#define PRIO0 __builtin_amdgcn_s_setprio(0)

__device__ __forceinline__ float bf2f(u16 u){
  union { unsigned int i; float f; } z; z.i = ((unsigned int)u) << 16; return z.f;
}
__device__ __forceinline__ u16 f2bf(float f){
  union { float f; unsigned int i; } z; z.f = f;
  unsigned int i = z.i;
  return (u16)((i + 0x7fffu + ((i >> 16) & 1u)) >> 16);
}
__device__ __forceinline__ float gelu_f(float x){
  return 0.5f * x * (1.0f + erff(x * 0.70710678118654752440f));
}
__device__ __forceinline__ void gl_lds16(const u16* g, u16* l){
  __builtin_amdgcn_global_load_lds((const __attribute__((address_space(1))) void*)(g),
                                   (__attribute__((address_space(3))) void*)(l), 16, 0, 0);
}

// ---------------- K0: weights -> bf16 (g1 folded into w_qkv) ----------------
__global__ void prep_w_k(const float* __restrict__ wqkv, const float* __restrict__ g1,
                         const float* __restrict__ wout, u16* __restrict__ w1b,
                         u16* __restrict__ w2b){
  int i = blockIdx.x * 256 + threadIdx.x;
  if (i < 1536*512) {
    w1b[i] = f2bf(wqkv[i] * g1[i & 511]);
  } else {
    int j = i - 1536*512;
    w2b[j] = f2bf(wout[j]);
  }
}

// ------- K1: ChanLN over c, single global read, bf16 LDS staging -----------
__global__ __launch_bounds__(512) void ln1t_k(const float* __restrict__ fmap,
                                              u16* __restrict__ xlnT){
  int b = blockIdx.y, n0 = blockIdx.x * 32;
  int t = threadIdx.x;
  int lane = t & 63, wv = t >> 6;
  __shared__ u16 Lb[512][40];
  __shared__ u16 Tt[64][36];
  __shared__ float red1[8][8][4], red2[8][8][4];
  __shared__ float mean_s[32], rstd_s[32];

  int ng = t & 7;
  float s1[4] = {0,0,0,0}, s2[4] = {0,0,0,0};
  const float* fb = fmap + ((size_t)b*CD)*NS + n0 + ng*4;
  #pragma unroll
  for (int it = 0; it < 8; ++it){
    int q = it*512 + t;
    int c = q >> 3;
    f32x4 v = *(const f32x4*)&fb[(size_t)c*NS];
    u16x4 pk;
    #pragma unroll
    for (int j = 0; j < 4; ++j){
      pk[j] = f2bf(v[j]);
      s1[j] += v[j]; s2[j] += v[j]*v[j];
    }
    *(u16x4*)&Lb[c][ng*4] = pk;
  }
  #pragma unroll
  for (int off = 8; off < 64; off <<= 1)
    #pragma unroll
    for (int j = 0; j < 4; ++j){
      s1[j] += __shfl_xor(s1[j], off, 64);
      s2[j] += __shfl_xor(s2[j], off, 64);
    }
  if (lane < 8){
    #pragma unroll
    for (int j = 0; j < 4; ++j){ red1[wv][lane][j] = s1[j]; red2[wv][lane][j] = s2[j]; }
  }
  __syncthreads();
  if (t < 32){
    int g = t >> 2, j = t & 3;
    float a = 0.f, bq = 0.f;
    #pragma unroll
    for (int w = 0; w < 8; ++w){ a += red1[w][g][j]; bq += red2[w][g][j]; }
    float mn = a * (1.f/512.f);
    float var = bq * (1.f/512.f) - mn*mn;
    mean_s[t] = mn; rstd_s[t] = rsqrtf(var + 1e-5f);
  }
  __syncthreads();

  for (int ct = 0; ct < 8; ++ct){
    {
      int cl = t >> 3, n4 = (t & 7) * 4;
      u16x4 xv = *(const u16x4*)&Lb[ct*64 + cl][n4];
      u16x4 pk;
      #pragma unroll
      for (int j = 0; j < 4; ++j)
        pk[j] = f2bf((bf2f(xv[j]) - mean_s[n4+j]) * rstd_s[n4+j]);
      *(u16x4*)&Tt[cl][n4] = pk;
    }
    __syncthreads();
    {
      int nr = t >> 4, c4 = t & 15;
      u16x4 w;
      #pragma unroll
      for (int j = 0; j < 4; ++j) w[j] = Tt[c4*4 + j][nr];
      *(u16x4*)&xlnT[((size_t)b*NS + n0 + nr)*CD + ct*64 + c4*4] = w;
    }
    __syncthreads();
  }
}

// ---------- K2a: q-GEMM (512 rows), r12 loop verbatim -----------------------
__global__ __launch_bounds__(512) void gemm1q_k(const u16* __restrict__ A,
                                                const u16* __restrict__ Bm,
                                                u16* __restrict__ Q){
  __shared__ u16 lds[8][8192];   // [slot*4+half]
  int bi = blockIdx.x;
  int xcd = bi & 7, r2 = bi >> 3;   // 0..63
  int yy = r2 & 1, gi = r2 >> 1;
  int g  = gi*8 + xcd;
  int x  = g & 15, z = g >> 4;
  int o0 = yy*256, bn0 = x*256;
  int t = threadIdx.x;
  int lane = t & 63, wv = t >> 6;
  int wm = wv >> 2, wn = wv & 3;
  int fr = lane & 15, fg = lane >> 4;
  const u16* Ab = A + (size_t)o0*512;
  const u16* Bb = Bm + ((size_t)z*NS + bn0)*512;
  int li8 = lane >> 3, scn = lane & 7;

  f32x4 acc[8][4];
  #pragma unroll
  for (int i=0;i<8;++i)
    #pragma unroll
    for (int j=0;j<4;++j) acc[i][j] = (f32x4){0.f,0.f,0.f,0.f};
  s16x8 afr[4][2];
  s16x8 bfr[2][2][2];

  auto stH = [&](int slot, int half, int kt){
    #pragma unroll
    for (int it=0; it<2; ++it){
      int li = it*64 + wv*8 + li8;
      int q  = scn ^ (li & 7);
      int row;
      if (half < 2) row = ((li>>6)<<7) + half*64 + (li & 63);
      else          row = ((li>>5)<<6) + (half-2)*32 + (li & 31);
      const u16* G = (half < 2) ? Ab : Bb;
      gl_lds16(G + (size_t)row*512 + kt + q*8, &lds[slot*4+half][it*4096 + wv*512]);
    }
  };
  auto ldA = [&](int slot, int mq){
    #pragma unroll
    for (int mr=0;mr<4;++mr)
      #pragma unroll
      for (int ks=0;ks<2;++ks){
        int li = wm*64 + mr*16 + fr;
        int c8 = (ks*4+fg) ^ (li & 7);
        afr[mr][ks] = *(const s16x8*)&lds[slot*4+mq][li*64 + c8*8];
      }
  };
  auto ldB = [&](int slot, int nq){
    #pragma unroll
    for (int nr=0;nr<2;++nr)
      #pragma unroll
      for (int ks=0;ks<2;++ks){
        int li = wn*32 + nr*16 + fr;
        int c8 = (ks*4+fg) ^ (li & 7);
        bfr[nq][nr][ks] = *(const s16x8*)&lds[slot*4+2+nq][li*64 + c8*8];
      }
  };
  auto mm = [&](int mq, int nq){
    #pragma unroll
    for (int mr=0;mr<4;++mr)
      #pragma unroll
      for (int nr=0;nr<2;++nr)
        #pragma unroll
        for (int ks=0;ks<2;++ks)
          acc[mq*4+mr][nq*2+nr] = __builtin_amdgcn_mfma_f32_16x16x32_bf16(
              afr[mr][ks], bfr[nq][nr][ks], acc[mq*4+mr][nq*2+nr], 0,0,0);
  };

  stH(0,0,0); stH(0,2,0); stH(0,3,0); stH(0,1,0);
  asm volatile("s_waitcnt vmcnt(2)" ::: "memory");
  SBAR; SCHED;

  #pragma unroll
  for (int kt=0; kt<8; ++kt){
    int slot = kt & 1, ns = slot ^ 1, kn = (kt+1)*64;
    bool F = kt < 7;
    ldA(slot,0); ldB(slot,0); ldB(slot,1);
    if (F){ stH(ns,0,kn); stH(ns,2,kn); stH(ns,3,kn); }
    PRIO1; mm(0,0); mm(0,1); PRIO0;
    if (F) asm volatile("s_waitcnt vmcnt(6)" ::: "memory");
    else   asm volatile("s_waitcnt vmcnt(0)" ::: "memory");
    SBAR; SCHED;
    ldA(slot,1);
    if (F) stH(ns,1,kn);
    PRIO1; mm(1,1); mm(1,0); PRIO0;
    if (F) asm volatile("s_waitcnt vmcnt(2)" ::: "memory");
    SBAR; SCHED;
  }

  size_t cb = (size_t)z * 512 * NS;
  #pragma unroll
  for (int mq=0;mq<2;++mq)
    #pragma unroll
    for (int mr=0;mr<4;++mr)
      #pragma unroll
      for (int nq=0;nq<2;++nq)
        #pragma unroll
        for (int nr=0;nr<2;++nr){
          int row = o0 + wm*128 + mq*64 + mr*16 + fg*4;
          int col = bn0 + wn*64 + nq*32 + nr*16 + fr;
          #pragma unroll
          for (int r=0;r<4;++r)
            Q[cb + (size_t)(row+r)*NS + col] = f2bf(acc[mq*4+mr][nq*2+nr][r]);
        }
}

// ---------- K2b: kv-GEMM + FUSED ctx partial (no k/v HBM round-trip) --------
__global__ __launch_bounds__(512) void gemm1kv_k(const u16* __restrict__ A,
                                                 const u16* __restrict__ Bm,
                                                 float* __restrict__ part,
                                                 float* __restrict__ mS){
  __shared__ u16 lds[8][8192];
  int bi = blockIdx.x;
  int xcd = bi & 7, r2 = bi >> 3;
  int hp = r2 & 3, gg = r2 >> 2;
  int g8 = gg*8 + xcd;
  int x  = g8 & 15, z = g8 >> 4;
  int bn0 = x*256;
  int t = threadIdx.x;
  int lane = t & 63, wv = t >> 6;
  int wm = wv >> 2, wn = wv & 3;
  int fr = lane & 15, fg = lane >> 4;
  const u16* Akb = A + (size_t)(512  + hp*128)*512;
  const u16* Avb = A + (size_t)(1024 + hp*128)*512;
  const u16* Bb  = Bm + ((size_t)z*NS + bn0)*512;
  int li8 = lane >> 3, scn = lane & 7;

  f32x4 acc[8][4];
  #pragma unroll
  for (int i=0;i<8;++i)
    #pragma unroll
    for (int j=0;j<4;++j) acc[i][j] = (f32x4){0.f,0.f,0.f,0.f};
  s16x8 afr[4][2];
  s16x8 bfr[2][2][2];

  auto stH = [&](int slot, int half, int kt){
    #pragma unroll
    for (int it=0; it<2; ++it){
      int li = it*64 + wv*8 + li8;
      int q  = scn ^ (li & 7);
      if (half < 2){
        int rr = half*64 + (li & 63);
        const u16* G = it ? Avb : Akb;
        gl_lds16(G + (size_t)rr*512 + kt + q*8, &lds[slot*4+half][it*4096 + wv*512]);
      } else {
        int row = ((li>>5)<<6) + (half-2)*32 + (li & 31);
        gl_lds16(Bb + (size_t)row*512 + kt + q*8, &lds[slot*4+half][it*4096 + wv*512]);
      }
    }
  };
  auto ldA = [&](int slot, int mq){
    #pragma unroll
    for (int mr=0;mr<4;++mr)
      #pragma unroll
      for (int ks=0;ks<2;++ks){
        int li = wm*64 + mr*16 + fr;
        int c8 = (ks*4+fg) ^ (li & 7);
        afr[mr][ks] = *(const s16x8*)&lds[slot*4+mq][li*64 + c8*8];
      }
  };
  auto ldB = [&](int slot, int nq){
    #pragma unroll
    for (int nr=0;nr<2;++nr)
      #pragma unroll
      for (int ks=0;ks<2;++ks){
        int li = wn*32 + nr*16 + fr;
        int c8 = (ks*4+fg) ^ (li & 7);
        bfr[nq][nr][ks] = *(const s16x8*)&lds[slot*4+2+nq][li*64 + c8*8];
      }
  };
  auto mm = [&](int mq, int nq){
    #pragma unroll
    for (int mr=0;mr<4;++mr)
      #pragma unroll
      for (int nr=0;nr<2;++nr)
        #pragma unroll
        for (int ks=0;ks<2;++ks)
          acc[mq*4+mr][nq*2+nr] = __builtin_amdgcn_mfma_f32_16x16x32_bf16(
              afr[mr][ks], bfr[nq][nr][ks], acc[mq*4+mr][nq*2+nr], 0,0,0);
  };

  stH(0,0,0); stH(0,2,0); stH(0,3,0); stH(0,1,0);
  asm volatile("s_waitcnt vmcnt(2)" ::: "memory");
  SBAR; SCHED;

  #pragma unroll
  for (int kt=0; kt<8; ++kt){
    int slot = kt & 1, ns = slot ^ 1, kn = (kt+1)*64;
    bool F = kt < 7;
    ldA(slot,0); ldB(slot,0); ldB(slot,1);
    if (F){ stH(ns,0,kn); stH(ns,2,kn); stH(ns,3,kn); }
    PRIO1; mm(0,0); mm(0,1); PRIO0;
    if (F) asm volatile("s_waitcnt vmcnt(6)" ::: "memory");
    else   asm volatile("s_waitcnt vmcnt(0)" ::: "memory");
    SBAR; SCHED;
    ldA(slot,1);
    if (F) stH(ns,1,kn);
    PRIO1; mm(1,1); mm(1,0); PRIO0;
    if (F) asm volatile("s_waitcnt vmcnt(2)" ::: "memory");
    SBAR; SCHED;
  }

  // ---- Phase 1: acc -> KT/VT tiles ----
  if (wm == 0){
    #pragma unroll
    for (int mq=0;mq<2;++mq)
      #pragma unroll
      for (int mr=0;mr<4;++mr)
        #pragma unroll
        for (int nj=0;nj<4;++nj){
          int nq = nj>>1, nr = nj&1;
          #pragma unroll
          for (int r=0;r<4;++r){
            int d  = mr*16 + fg*4 + r;
            int nl = wn*64 + nq*32 + nr*16 + fr;
            int hh = nl >> 7, n1 = nl & 127;
            lds[mq*2+hh][d*128 + (n1 ^ ((d&7)<<3))] = f2bf(__expf(acc[mq*4+mr][nj][r]));
          }
        }
  } else {
    float ss[2][4];
    #pragma unroll
    for (int mq=0;mq<2;++mq)
      #pragma unroll
      for (int nj=0;nj<4;++nj){
        float s = 0.f;
        #pragma unroll
        for (int mr=0;mr<4;++mr)
          #pragma unroll
          for (int r=0;r<4;++r){ float v = acc[mq*4+mr][nj][r]; s += v*v; }
        s += __shfl_xor(s, 16, 64);
        s += __shfl_xor(s, 32, 64);
        ss[mq][nj] = rsqrtf(s);
      }
    #pragma unroll
    for (int mq=0;mq<2;++mq)
      #pragma unroll
      for (int mr=0;mr<4;++mr)
        #pragma unroll
        for (int nj=0;nj<4;++nj){
          int nq = nj>>1, nr = nj&1;
          #pragma unroll
          for (int r=0;r<4;++r){
            int e  = mr*16 + fg*4 + r;
            int nl = wn*64 + nq*32 + nr*16 + fr;
            int hh = nl >> 7, n1 = nl & 127;
            lds[4 + mq*2+hh][e*128 + (n1 ^ ((e&7)<<3))] = f2bf(acc[mq*4+mr][nj][r] * ss[mq][nj]);
          }
        }
  }
  __syncthreads();

  // ---- Phase 2: ctx MFMA + sloc ----
  int eg = wv >> 2, ej = wv & 3, ksl = ej & 1;
  const u16* KTt = &lds[eg*2 + (ej>>1)][0];
  const u16* VTt = &lds[4 + eg*2 + (ej>>1)][0];
  f32x4 a2[4][4];
  #pragma unroll
  for (int i=0;i<4;++i)
    #pragma unroll
    for (int j=0;j<4;++j) a2[i][j] = (f32x4){0.f,0.f,0.f,0.f};
  #pragma unroll
  for (int ks2=0; ks2<2; ++ks2){
    int kc = ksl*64 + ks2*32 + fg*8;
    s16x8 af[4], bf_[4];
    #pragma unroll
    for (int i=0;i<4;++i){
      int ra = i*16 + fr;
      af[i]  = *(const s16x8*)&KTt[ra*128 + (kc ^ ((ra&7)<<3))];
      bf_[i] = *(const s16x8*)&VTt[ra*128 + (kc ^ ((ra&7)<<3))];
    }
    #pragma unroll
    for (int i=0;i<4;++i)
      #pragma unroll
      for (int j=0;j<4;++j)
        a2[i][j] = __builtin_amdgcn_mfma_f32_16x16x32_bf16(af[i], bf_[j], a2[i][j], 0,0,0);
  }
  float slc = 0.f;
  {
    int d = lane;
    #pragma unroll
    for (int cc=0; cc<8; ++cc){
      int c0 = ksl*64 + cc*8;
      u16x8 vv = *(const u16x8*)&KTt[d*128 + (c0 ^ ((d&7)<<3))];
      #pragma unroll
      for (int jj=0;jj<8;++jj) slc += bf2f(vv[jj]);
    }
  }
  __syncthreads();

  // ---- Phase 3: dumps + slocB ----
  if (ej >= 1){
    float* dbuf = (float*)&lds[eg*3 + (ej-1)][0];
    #pragma unroll
    for (int i=0;i<4;++i)
      #pragma unroll
      for (int j=0;j<4;++j)
        #pragma unroll
        for (int r=0;r<4;++r) dbuf[((i*4+j)*4+r)*64 + lane] = a2[i][j][r];
  }
  ((float*)&lds[6][0])[eg*256 + ej*64 + lane] = slc;
  __syncthreads();

  // ---- Phase 4: reduce + write ----
  int bh = z*8 + hp*2 + eg;
  size_t base = (size_t)bh*16 + x;
  if (ej == 0){
    #pragma unroll
    for (int bb=0; bb<3; ++bb){
      float* dbuf = (float*)&lds[eg*3 + bb][0];
      #pragma unroll
      for (int i=0;i<4;++i)
        #pragma unroll
        for (int j=0;j<4;++j)
          #pragma unroll
          for (int r=0;r<4;++r) a2[i][j][r] += dbuf[((i*4+j)*4+r)*64 + lane];
    }
    float* pp = part + base*4096;
    #pragma unroll
    for (int i=0;i<4;++i)
      #pragma unroll
      for (int j=0;j<4;++j)
        #pragma unroll
        for (int r=0;r<4;++r)
          pp[(i*16+fg*4+r)*64 + j*16+fr] = a2[i][j][r];
  } else if (ej == 1){
    float* sB = (float*)&lds[6][0];
    float s = sB[eg*256 + lane] + sB[eg*256 + 64 + lane]
            + sB[eg*256 + 128 + lane] + sB[eg*256 + 192 + lane];
    mS[base*128 + lane]      = 0.0f;
    mS[base*128 + 64 + lane] = s;
  }
}

// ---- K4b: merge 16 chunk partials -> ctx -----------------------------------
__global__ void ctxred_k(const float* __restrict__ part, const float* __restrict__ mS,
                         float* __restrict__ ctx){
  int bh = blockIdx.x, t = threadIdx.x;
  __shared__ float fs[16][64];
  if (t < 64){
    int d = t;
    float denom = 0.f;
    #pragma unroll
    for (int c=0;c<16;++c)
      denom += mS[((size_t)bh*16 + c)*128 + 64 + d];
    float inv = 1.0f / (denom * 4096.0f);
    #pragma unroll
    for (int c=0;c<16;++c) fs[c][d] = inv;
  }
  __syncthreads();
  #pragma unroll
  for (int i=0;i<16;++i){
    int idx = t + i*256;
    int d = idx >> 6;
    float s = 0.f;
    #pragma unroll
    for (int ch=0; ch<16; ++ch) s += fs[ch][d] * part[((size_t)bh*16 + ch)*4096 + idx];
    ctx[(size_t)bh*4096 + idx] = s;
  }
}

// --- K6: FUSED attn-out + GEMM2 + final ChanLN -> d_out ---------------------
// r18 structure (A-ring gl_lds staging, 107us) + ONE change: attn MFMA
// operand-swapped (out[e][n]) so gelu->Bh writes are u16x4 vectors
// (was 16 scalar stores -> 2.9M bank-conflict cycles).
__global__ __launch_bounds__(512) void gemm2f_k(const u16* __restrict__ A,
                                                const u16* __restrict__ q,
                                                const float* __restrict__ ctx,
                                                const float* __restrict__ g2,
                                                float* __restrict__ out){
  __shared__ u16 Ar[2][16384];
  __shared__ u16 Bh[2][4096];
  __shared__ u16 P[128][72];
  __shared__ u16 cT[64][72];
  __shared__ float invP[128];
  int x = blockIdx.x, z = blockIdx.y;
  int n0 = x*128;
  int t = threadIdx.x;
  int lane = t & 63, wv = t >> 6;
  int wm = wv >> 1, wn = wv & 1;     // GEMM map: 4M x 2N
  int we2 = wv >> 2, nn = wv & 3;    // attn map: 2E x 4N
  int fr = lane & 15, fg = lane >> 4;
  int l8 = lane >> 3, c8d = lane & 7;
  const u16* Ab = A;

  f32x4 acc[8][4];
  #pragma unroll
  for (int i=0;i<8;++i)
    #pragma unroll
    for (int j=0;j<4;++j) acc[i][j] = (f32x4){0.f,0.f,0.f,0.f};
  s16x8 afr[4], bfr[4];

  auto stA4 = [&](int slot, int kt){
    #pragma unroll
    for (int bt=0; bt<4; ++bt){
      int L  = bt*64 + wv*8 + l8;
      int qq = c8d ^ (l8 & 7);
      int r  = (qq >> 2)*256 + L;
      int col = kt + (qq & 3)*8;
      gl_lds16(Ab + (size_t)r*512 + col, &Ar[slot][(bt*64 + wv*8)*64]);
    }
  };
  auto ldA = [&](int slot, int h2){
    #pragma unroll
    for (int mi=0;mi<4;++mi){
      int R = wm*128 + (h2*4+mi)*16 + fr;
      int L = R & 255, half = R >> 8;
      int c8 = (half*4 + fg) ^ (L & 7);
      afr[mi] = *(const s16x8*)&Ar[slot][L*64 + c8*8];
    }
  };
  auto ldBh = [&](int kt2){
    #pragma unroll
    for (int nj=0;nj<4;++nj){
      int R = wn*64 + nj*16 + fr;
      int L = R & 63, hh = R >> 6;
      int c8 = (hh*4 + fg) ^ (L & 7);
      bfr[nj] = *(const s16x8*)&Bh[kt2][L*64 + c8*8];
    }
  };
  auto mm16 = [&](int h2){
    #pragma unroll
    for (int mi=0;mi<4;++mi)
      #pragma unroll
      for (int nj=0;nj<4;++nj)
        acc[h2*4+mi][nj] = __builtin_amdgcn_mfma_f32_16x16x32_bf16(
            afr[mi], bfr[nj], acc[h2*4+mi][nj], 0,0,0);
  };

  stA4(0, 0);

  for (int h = 0; h < 8; ++h){
    const float* cs = ctx + ((size_t)(z*8 + h))*4096;
    #pragma unroll
    for (int i=0;i<8;++i){
      int idx = i*512 + t;
      cT[idx & 63][idx >> 6] = f2bf(cs[idx]);
    }
    {
      int nl = wv*16 + fr;
      const u16* qb = q + ((size_t)(z*512 + h*64 + fg*16))*NS + n0 + nl;
      float p[16];
      float m = -3.0e38f;
      #pragma unroll
      for (int j=0;j<16;++j){ p[j] = bf2f(qb[(size_t)j*NS]); m = fmaxf(m, p[j]); }
      m = fmaxf(m, __shfl_xor(m, 16, 64));
      m = fmaxf(m, __shfl_xor(m, 32, 64));
      float s = 0.f;
      #pragma unroll
      for (int j=0;j<16;++j){ p[j] = __expf(p[j]-m); s += p[j]; }
      s += __shfl_xor(s, 16, 64);
      s += __shfl_xor(s, 32, 64);
      u16x8 pk;
      #pragma unroll
      for (int j=0;j<8;++j) pk[j] = f2bf(p[j]);
      *(u16x8*)&P[nl][fg*16] = pk;
      #pragma unroll
      for (int j=0;j<8;++j) pk[j] = f2bf(p[8+j]);
      *(u16x8*)&P[nl][fg*16+8] = pk;
      if (fg == 0) invP[nl] = 0.125f / s;
    }
    __syncthreads();                 // (A): P,cT ready; prev s1 reads done
    stA4(1, (2*h+1)*32);             // s1 <- A[2h+1]

    // attn MFMA (swapped): out[e][n]; wave (we2,nn) covers e 32 x n 32
    f32x4 a2[2][2];
    #pragma unroll
    for (int i=0;i<2;++i)
      #pragma unroll
      for (int j=0;j<2;++j) a2[i][j] = (f32x4){0.f,0.f,0.f,0.f};
    #pragma unroll
    for (int ks=0; ks<2; ++ks){
      s16x8 afx[2], bfx[2];
      #pragma unroll
      for (int ei=0;ei<2;++ei)
        afx[ei] = *(const s16x8*)&cT[we2*32 + ei*16 + fr][ks*32 + fg*8];
      #pragma unroll
      for (int ni=0;ni<2;++ni)
        bfx[ni] = *(const s16x8*)&P[nn*32 + ni*16 + fr][ks*32 + fg*8];
      #pragma unroll
      for (int ei=0;ei<2;++ei)
        #pragma unroll
        for (int ni=0;ni<2;++ni)
          a2[ei][ni] = __builtin_amdgcn_mfma_f32_16x16x32_bf16(afx[ei], bfx[ni], a2[ei][ni], 0,0,0);
    }
    // gelu -> Bh (u16x4 vector writes, ldBh-consumable layout)
    #pragma unroll
    for (int ei=0;ei<2;++ei)
      #pragma unroll
      for (int ni=0;ni<2;++ni){
        int n = nn*32 + ni*16 + fr;
        float ip = invP[n];
        u16x4 w4;
        #pragma unroll
        for (int r=0;r<4;++r) w4[r] = f2bf(gelu_f(a2[ei][ni][r] * ip));
        int e32 = we2*32 + ei*16 + fg*4;       // e within head [0,64)
        int kt2w = e32 >> 5;                    // k-tile (e/32)
        int ec = e32 & 31;                      // e within tile
        int chunk = ec >> 3, sub = ec & 7;
        int L = n & 63, hh = n >> 6;
        int c8 = (hh*4 + chunk) ^ (L & 7);
        *(u16x4*)&Bh[kt2w][L*64 + c8*8 + sub] = w4;
      }
    asm volatile("s_waitcnt vmcnt(4)" ::: "memory");   // s0 (A[2h]) landed
    __syncthreads();                                   // (B): Bh visible
    // GEMM k-tile 2h (s0)
    ldA(0,0); ldBh(0);
    PRIO1; mm16(0); PRIO0;
    ldA(0,1);
    PRIO1; mm16(1); PRIO0;
    asm volatile("s_waitcnt vmcnt(0)" ::: "memory");   // s1 landed
    __syncthreads();                                   // all done reading s0
    if (h < 7) stA4(0, (2*h+2)*32);
    // GEMM k-tile 2h+1 (s1)
    ldA(1,0); ldBh(1);
    PRIO1; mm16(0); PRIO0;
    ldA(1,1);
    PRIO1; mm16(1); PRIO0;
  }

  __syncthreads();
  float* red1 = (float*)&Ar[0][0];
  float* red2 = red1 + 512;
  float* ms   = red2 + 512;
  float* rs   = ms + 128;
  float s1[4], s2[4];
  #pragma unroll
  for (int nj=0;nj<4;++nj){
    float a = 0.f, b2 = 0.f;
    #pragma unroll
    for (int mi=0;mi<8;++mi)
      #pragma unroll
      for (int r=0;r<4;++r){ float v = acc[mi][nj][r]; a += v; b2 += v*v; }
    s1[nj] = a; s2[nj] = b2;
  }
  #pragma unroll
  for (int off=16; off<64; off<<=1)
    #pragma unroll
    for (int nj=0;nj<4;++nj){
      s1[nj] += __shfl_xor(s1[nj], off, 64);
      s2[nj] += __shfl_xor(s2[nj], off, 64);
    }
  if (fg == 0){
    #pragma unroll
    for (int nj=0;nj<4;++nj){
      int c = wn*64 + nj*16 + fr;
      red1[wm*128 + c] = s1[nj];
      red2[wm*128 + c] = s2[nj];
    }
  }
  __syncthreads();
  if (t < 128){
    float a  = red1[t] + red1[128+t] + red1[256+t] + red1[384+t];
    float b2 = red2[t] + red2[128+t] + red2[256+t] + red2[384+t];
    float mn = a * (1.f/512.f);
    float var = b2 * (1.f/512.f) - mn*mn;
    ms[t] = mn; rs[t] = rsqrtf(var + 1e-5f);
  }
  __syncthreads();
  float mc[4], rc[4];
  #pragma unroll
  for (int nj=0;nj<4;++nj){
    int c = wn*64 + nj*16 + fr;
    mc[nj] = ms[c]; rc[nj] = rs[c];
  }
  float* ob = out + (size_t)z*CD*NS + n0;
  #pragma unroll
  for (int mi=0;mi<8;++mi)
    #pragma unroll
    for (int r=0;r<4;++r){
      int row = wm*128 + mi*16 + fg*4 + r;
      float gg = g2[row];
      #pragma unroll
      for (int nj=0;nj<4;++nj)
        ob[(size_t)row*NS + wn*64 + nj*16 + fr] = (acc[mi][nj][r] - mc[nj])*rc[nj]*gg;
    }
}

extern "C" void kernel_launch(void* const* d_in, const int* in_sizes, int n_in,
                              void* d_out, int out_size, void* d_ws, size_t ws_size,
                              hipStream_t stream) {
  const float* fmap = (const float*)d_in[0];
  const float* g1   = (const float*)d_in[1];
  const float* wqkv = (const float*)d_in[2];
  const float* wout = (const float*)d_in[3];
  const float* g2   = (const float*)d_in[4];
  float* out = (float*)d_out;

  char* ws = (char*)d_ws;
  size_t off = 0;
  auto alloc = [&](size_t bytes) -> void* {
    void* p = ws + off;
    off += (bytes + 255) & ~(size_t)255;
    return p;
  };
  u16*   q    = (u16*)alloc((size_t)16*512*4096*2);
  u16*   xlnT = (u16*)alloc((size_t)16*4096*512*2);
  float* part = (float*)alloc((size_t)128*16*4096*4);
  float* mS   = (float*)alloc((size_t)128*16*128*4);
  float* ctx  = (float*)alloc((size_t)128*4096*4);
  u16*   w1b  = (u16*)alloc((size_t)1536*512*2);
  u16*   w2b  = (u16*)alloc((size_t)512*512*2);
  if (off > ws_size) return;

  prep_w_k<<<4096, 256, 0, stream>>>(wqkv, g1, wout, w1b, w2b);
  ln1t_k<<<dim3(128,16), 512, 0, stream>>>(fmap, xlnT);
  gemm1q_k<<<512, 512, 0, stream>>>(w1b, xlnT, q);
  gemm1kv_k<<<1024, 512, 0, stream>>>(w1b, xlnT, part, mS);
  ctxred_k<<<128, 256, 0, stream>>>(part, mS, ctx);
  gemm2f_k<<<dim3(32,16), 512, 0, stream>>>(w2b, q, ctx, g2, out);
}